// Round 4
// baseline (393.843 us; speedup 1.0000x reference)
//
#include <hip/hip_runtime.h>

// RecurrentResonanceModel on MI355X.
// Pipeline:
//   k_convert    : x, W_sel fp32 -> bf16; Wmom -> WmomT fp32 (transposed)
//   k_head_gemm  : logits[m][a] = x[m][:] . Wsel[a][:]  (MFMA, f32 out)
//   k_softmax_mom: softmax(logits)+bsel -> sel bf16; mom head fp32
//   k_transpose  : atoms fp32 [A][S] -> bf16 [S][A]
//   k_gemm       : res[m][s] = sel[m][:] . atomsT[s][:]
//                  256x256 tile, BK=32, 4 waves x 128x128/wave (halves LDS
//                  read traffic vs 8x128x64), 2-buffer rotation in 64 KiB LDS
//                  -> 2 blocks/CU co-resident: cross-block LDS||MFMA overlap.
//                  Counted vmcnt(8), XOR-swizzled LDS (pre-swizzled global
//                  src, linear LDS dest), setprio around MFMA, XCD-bijective
//                  grid, swizzled LDS-staged epilogue in 2 half-tile rounds.
//   k_final      : single-pass chunk norms (P0/P1) + scale + overlap-add
//
// Sizes: M=1024 (B*E), L=128, A=1024, S=32768, F=128, W=512, HOP=256.
// d_out = [ out (1024*32768 f32) | mom (1024*128 f32) ]
// d_ws  = [ atomsT bf16 64MB | sel bf16 2MB | res bf16 64MB ]

typedef __attribute__((ext_vector_type(8))) short short8;
typedef __attribute__((ext_vector_type(4))) float f32x4;

typedef __attribute__((address_space(1))) void GV;
typedef __attribute__((address_space(3))) void LV;

__device__ __forceinline__ unsigned short f2bf(float f) {
    union { float f; unsigned u; } c; c.f = f;
    unsigned u = c.u;
    u = (u + 0x7FFFu + ((u >> 16) & 1u)) >> 16;   // RNE
    return (unsigned short)u;
}
__device__ __forceinline__ float bf2f(unsigned short h) {
    union { unsigned u; float f; } c; c.u = ((unsigned)h) << 16; return c.f;
}

// ---------------------------------------------------------------- convert
__global__ __launch_bounds__(256) void k_convert(
        const float* __restrict__ x, const float* __restrict__ Wsel,
        const float* __restrict__ Wmom,
        unsigned short* __restrict__ xbf, unsigned short* __restrict__ wbf,
        float* __restrict__ WmomT) {
    const int i = (blockIdx.x * 256 + threadIdx.x) * 4;
    {
        float4 v = *(const float4*)(x + i);
        uint2 q;
        q.x = (unsigned)f2bf(v.x) | ((unsigned)f2bf(v.y) << 16);
        q.y = (unsigned)f2bf(v.z) | ((unsigned)f2bf(v.w) << 16);
        *(uint2*)(xbf + i) = q;
    }
    {
        float4 v = *(const float4*)(Wsel + i);
        uint2 q;
        q.x = (unsigned)f2bf(v.x) | ((unsigned)f2bf(v.y) << 16);
        q.y = (unsigned)f2bf(v.z) | ((unsigned)f2bf(v.w) << 16);
        *(uint2*)(wbf + i) = q;
    }
    if (blockIdx.x < 8) {
        const int f  = blockIdx.x * 16 + (threadIdx.x >> 4);   // 0..127
        const int kc = (threadIdx.x & 15) * 8;                 // 0..120
        float4 a = *(const float4*)(Wmom + (size_t)f * 128 + kc);
        float4 b = *(const float4*)(Wmom + (size_t)f * 128 + kc + 4);
        WmomT[(kc + 0) * 128 + f] = a.x; WmomT[(kc + 1) * 128 + f] = a.y;
        WmomT[(kc + 2) * 128 + f] = a.z; WmomT[(kc + 3) * 128 + f] = a.w;
        WmomT[(kc + 4) * 128 + f] = b.x; WmomT[(kc + 5) * 128 + f] = b.y;
        WmomT[(kc + 6) * 128 + f] = b.z; WmomT[(kc + 7) * 128 + f] = b.w;
    }
}

// ---------------------------------------------------------------- head gemm
__global__ __launch_bounds__(256) void k_head_gemm(
        const unsigned short* __restrict__ A, const unsigned short* __restrict__ Bm,
        float* __restrict__ logits) {
    __shared__ __align__(16) unsigned short lA[128 * 32];
    __shared__ __align__(16) unsigned short lB[128 * 32];
    const int tid = threadIdx.x;
    const int wave = tid >> 6;
    const int lane = tid & 63;
    const int l15 = lane & 15, quad = lane >> 4;
    const int i0 = blockIdx.x * 128;   // a (Wsel rows)
    const int j0 = blockIdx.y * 128;   // m (x rows)
    const int wi = wave >> 1, wj = wave & 1;
    const int rsel = lane >> 2;
    const int koff = (lane & 3) * 8;

    f32x4 acc[4][4] = {};

    for (int kt = 0; kt < 4; ++kt) {
        const int kbase = kt * 32;
#pragma unroll
        for (int c = 0; c < 2; ++c) {
            const int row = c * 64 + wave * 16 + rsel;
            const unsigned short* ga = A + (size_t)(i0 + row) * 128 + kbase + koff;
            const unsigned short* gb = Bm + (size_t)(j0 + row) * 128 + kbase + koff;
            unsigned short* la = lA + (c * 64 + wave * 16) * 32;
            unsigned short* lb = lB + (c * 64 + wave * 16) * 32;
            __builtin_amdgcn_global_load_lds((GV*)ga, (LV*)la, 16, 0, 0);
            __builtin_amdgcn_global_load_lds((GV*)gb, (LV*)lb, 16, 0, 0);
        }
        __syncthreads();

        short8 af[4], bf[4];
#pragma unroll
        for (int ti = 0; ti < 4; ++ti)
            af[ti] = *(const short8*)(lA + (wi * 64 + ti * 16 + l15) * 32 + quad * 8);
#pragma unroll
        for (int tj = 0; tj < 4; ++tj)
            bf[tj] = *(const short8*)(lB + (wj * 64 + tj * 16 + l15) * 32 + quad * 8);
#pragma unroll
        for (int ti = 0; ti < 4; ++ti)
#pragma unroll
            for (int tj = 0; tj < 4; ++tj)
                acc[ti][tj] = __builtin_amdgcn_mfma_f32_16x16x32_bf16(
                    af[ti], bf[tj], acc[ti][tj], 0, 0, 0);
        __syncthreads();
    }

#pragma unroll
    for (int ti = 0; ti < 4; ++ti) {
#pragma unroll
        for (int tj = 0; tj < 4; ++tj) {
            const int mrow = j0 + wj * 64 + tj * 16 + l15;
            const int abase = i0 + wi * 64 + ti * 16 + quad * 4;
            f32x4 v = acc[ti][tj];
            float4 o; o.x = v[0]; o.y = v[1]; o.z = v[2]; o.w = v[3];
            *(float4*)(logits + (size_t)mrow * 1024 + abase) = o;
        }
    }
}

// ---------------------------------------------------------------- softmax+mom
__global__ __launch_bounds__(256) void k_softmax_mom(
        const float* __restrict__ logits_g, const float* __restrict__ bsel,
        const float* __restrict__ x, const float* __restrict__ WmomT,
        const float* __restrict__ bmom, unsigned short* __restrict__ sel,
        float* __restrict__ momout) {
    __shared__ float xs[128];
    __shared__ float logits[1024];
    __shared__ float mvals[128];
    __shared__ float wred[4];
    __shared__ float sstat[2];
    const int tid = threadIdx.x;
    const int m = blockIdx.x;

    if (tid < 32) *(float4*)&xs[tid * 4] = *(const float4*)(x + (size_t)m * 128 + tid * 4);
    for (int a = tid; a < 1024; a += 256)
        logits[a] = logits_g[(size_t)m * 1024 + a] + bsel[a];
    __syncthreads();

    if (tid < 128) {
        float acc = bmom[tid];
#pragma unroll 8
        for (int k = 0; k < 128; ++k)
            acc += xs[k] * WmomT[k * 128 + tid];     // lane-coalesced
        float sig = 1.f / (1.f + __expf(-acc));
        mvals[tid] = 0.2f + sig * 0.72f;      // BASE_RES + sigmoid*RES_FACTOR
    }

    float mx = -1e30f;
    for (int a = tid; a < 1024; a += 256) mx = fmaxf(mx, logits[a]);
#pragma unroll
    for (int off = 32; off; off >>= 1) mx = fmaxf(mx, __shfl_xor(mx, off, 64));
    if ((tid & 63) == 0) wred[tid >> 6] = mx;
    __syncthreads();
    if (tid == 0) sstat[0] = fmaxf(fmaxf(wred[0], wred[1]), fmaxf(wred[2], wred[3]));
    __syncthreads();
    mx = sstat[0];

    float psum = 0.f;
    for (int a = tid; a < 1024; a += 256) {
        float e = __expf(logits[a] - mx);
        logits[a] = e;
        psum += e;
    }
#pragma unroll
    for (int off = 32; off; off >>= 1) psum += __shfl_xor(psum, off, 64);
    if ((tid & 63) == 0) wred[tid >> 6] = psum;
    __syncthreads();
    if (tid == 0) sstat[1] = wred[0] + wred[1] + wred[2] + wred[3];
    __syncthreads();
    const float inv = 1.f / sstat[1];
    for (int a = tid; a < 1024; a += 256)
        sel[(size_t)m * 1024 + a] = f2bf(logits[a] * inv);

    if (tid == 0) {
        float p = 1.f;
        for (int f = 0; f < 128; ++f) {
            p *= (mvals[f] + 1e-12f);
            momout[(size_t)m * 128 + f] = p;
        }
    }
}

// ---------------------------------------------------------------- transpose
__global__ __launch_bounds__(256) void k_transpose(
        const float* __restrict__ atoms, unsigned short* __restrict__ atomsT) {
    __shared__ float t[64][65];
    const int tid = threadIdx.x;
    const int s0 = blockIdx.x * 64;
    const int a0 = blockIdx.y * 64;

    {
        const int r0 = tid >> 4;
        const int c4 = (tid & 15) * 4;
        for (int rr = r0; rr < 64; rr += 16) {
            float4 v = *(const float4*)(atoms + (size_t)(a0 + rr) * 32768 + s0 + c4);
            t[rr][c4] = v.x; t[rr][c4 + 1] = v.y; t[rr][c4 + 2] = v.z; t[rr][c4 + 3] = v.w;
        }
    }
    __syncthreads();
    {
        const int sl = tid >> 2;
        const int seg = (tid & 3) * 16;
        unsigned short* dst = atomsT + (size_t)(s0 + sl) * 1024 + a0 + seg;
        unsigned pk[8];
#pragma unroll
        for (int i = 0; i < 16; i += 2) {
            unsigned short h0 = f2bf(t[seg + i][sl]);
            unsigned short h1 = f2bf(t[seg + i + 1][sl]);
            pk[i >> 1] = (unsigned)h0 | ((unsigned)h1 << 16);
        }
        uint4 q0; q0.x = pk[0]; q0.y = pk[1]; q0.z = pk[2]; q0.w = pk[3];
        uint4 q1; q1.x = pk[4]; q1.y = pk[5]; q1.z = pk[6]; q1.w = pk[7];
        *(uint4*)(dst) = q0;
        *(uint4*)(dst + 8) = q1;
    }
}

// ---------------------------------------------------------------- main gemm
// res[m][s] = sum_a sel[m][a] * atomsT[s][a].
// BM=256 (s), BN=256 (m), BK=32, 256 threads = 4 waves, per-wave 128x128
// (wm = s half, wn = m half), acc[8][8] f32x4.
// LDS-read traffic: 4 waves x (128+128) rows x 64 B = 64 KB/K-tile (vs 96 KB
// for 8x128x64) -> LDS pipe (~750 cyc) < MFMA pipe (~1242 cyc).
// LDS: 2 buffers x 16384 shorts = 64 KiB -> 2 blocks/CU; co-resident blocks
// drift out of phase so one block's ds_read burst hides under the other's
// MFMA cluster (m114 mechanism). All 512 blocks resident in one round.
// Counted vmcnt: STAGE = 8 glds instrs/thread; prologue 2 tiles (16), per
// tile vmcnt(8) = next tile in flight; tail vmcnt(0) at t=31.
// Per tile: vmcnt(8); barrier; 16 ds_read; lgkmcnt(0); barrier (WAR: buf
// fully read before STAGE(t+2) overwrites it); STAGE(t+2); 64 MFMA.
// Swizzle: within each 128-B super-row (2 rows of 32 k), 16-B granule
// G' = G ^ (q&7); applied to the *global source* of global_load_lds (LDS
// dest stays linear) and to the ds_read addresses (same involution).
__global__ __launch_bounds__(256, 1) void k_gemm(
        const unsigned short* __restrict__ A, const unsigned short* __restrict__ Bm,
        unsigned short* __restrict__ res) {
    // K-loop: 2 buffers x 16384 shorts (A 8192 | B 8192) = 65536 B.
    // Epilogue: [128 m][256 s] shorts half-tile (granule-XOR swizzled),
    // 2 rounds = 65536 B (reuse).
    __shared__ __align__(16) unsigned short smem[32768];
    const int tid = threadIdx.x;
    const int lane = tid & 63;
    const int wave = tid >> 6;
    const int l15 = lane & 15, quad = lane >> 4;
    const int wm = wave >> 1;          // 0..1 : s half (128 rows)
    const int wn = wave & 1;           // 0..1 : m half (128 rows)

    // bijective XCD swizzle (512 blocks, 512%8==0): chunks of 64 per XCD,
    // m-fast inside a chunk so 4 m-tiles share each atomsT panel in L2.
    const int wg = ((blockIdx.x & 7) << 6) | (blockIdx.x >> 3);
    const int m_tile = wg & 3;         // 0..3
    const int s_tile = wg >> 2;        // 0..127
    const int i0 = s_tile << 8;        // s base (atomsT rows)
    const int j0 = m_tile << 8;        // m base (sel rows)

    // Staging: 4 load instrs per operand region per tile; instr r covers LDS
    // bytes [r*4096 + tid*16, +16) of the region (linear dest; per-wave
    // uniform-base + lane*16 as required). Slot (q = byte>>7, G' = (byte>>4)&7)
    // holds content G = G'^(q&7): row = 2q + (G>>2), k-granule g = G&3 ->
    // pre-swizzled global source address.
    const unsigned short* gA[4];
    const unsigned short* gB[4];
    int st_ld[4];
#pragma unroll
    for (int r = 0; r < 4; ++r) {
        const int qq = r * 32 + (tid >> 3);
        const int Gs = (tid & 7) ^ (qq & 7);
        const int row = 2 * qq + (Gs >> 2);
        const int g8 = (Gs & 3) * 8;
        st_ld[r] = r * 2048 + tid * 8;                       // shorts
        gA[r] = A  + (size_t)(i0 + row) * 1024 + g8;
        gB[r] = Bm + (size_t)(j0 + row) * 1024 + g8;
    }

    // Fragment read offsets (swizzled): invariant across ti/tj; step 512
    // shorts (16 rows) per fragment index. Per-8-lane groups tile all 8
    // granule positions -> conflict-free ds_read_b128.
    const int Gp = (((l15 & 1) << 2) | quad) ^ (l15 >> 1);
    const int aoff = wm * 4096 + (l15 >> 1) * 64 + Gp * 8;   // shorts in A region
    const int boff = wn * 4096 + (l15 >> 1) * 64 + Gp * 8;   // shorts in B region

#define STAGE(T) {                                                            \
    unsigned short* bb = smem + ((T) & 1) * 16384;                            \
    const int kb = (T) * 32;                                                  \
    _Pragma("unroll")                                                         \
    for (int r = 0; r < 4; ++r) {                                             \
        __builtin_amdgcn_global_load_lds((GV*)(gA[r] + kb),                   \
            (LV*)(bb + st_ld[r]), 16, 0, 0);                                  \
        __builtin_amdgcn_global_load_lds((GV*)(gB[r] + kb),                   \
            (LV*)(bb + 8192 + st_ld[r]), 16, 0, 0);                           \
    } }

#define TILE(T, VMC, DOSTAGE) {                                               \
    asm volatile("s_waitcnt vmcnt(" VMC ")" ::: "memory");                    \
    __builtin_amdgcn_s_barrier();                                             \
    const unsigned short* bufA = smem + ((T) & 1) * 16384;                    \
    const unsigned short* bufB = bufA + 8192;                                 \
    short8 a8[8], b8[8];                                                      \
    _Pragma("unroll")                                                         \
    for (int tj = 0; tj < 8; ++tj)                                            \
        b8[tj] = *(const short8*)(bufB + boff + tj * 512);                    \
    _Pragma("unroll")                                                         \
    for (int ti = 0; ti < 8; ++ti)                                            \
        a8[ti] = *(const short8*)(bufA + aoff + ti * 512);                    \
    asm volatile("s_waitcnt lgkmcnt(0)" ::: "memory");                        \
    __builtin_amdgcn_s_barrier();                                             \
    if (DOSTAGE) STAGE((T) + 2);                                              \
    __builtin_amdgcn_s_setprio(1);                                            \
    _Pragma("unroll")                                                         \
    for (int ti = 0; ti < 8; ++ti)                                            \
    _Pragma("unroll")                                                         \
    for (int tj = 0; tj < 8; ++tj)                                            \
        acc[ti][tj] = __builtin_amdgcn_mfma_f32_16x16x32_bf16(                \
            a8[ti], b8[tj], acc[ti][tj], 0, 0, 0);                            \
    __builtin_amdgcn_s_setprio(0); }

    f32x4 acc[8][8] = {};

    STAGE(0); STAGE(1);                         // 16 loads in flight
    for (int t = 0; t < 30; ++t)
        TILE(t, "8", true);                     // stage t+2, next tile in flight
    TILE(30, "8", false);
    TILE(31, "0", false);

#undef TILE
#undef STAGE

    // Epilogue: two rounds (m halves). Round h: waves with wn==h write their
    // acc into LDS [128 m][256 s] bf16 with granule-XOR swizzle (8-B granule
    // g -> g ^ (mloc&15), involution), then all threads do row-coalesced
    // full-line global stores. Tile-31's post-read barrier guarantees all
    // K-loop ds_reads completed before the first overwrite.
    for (int h = 0; h < 2; ++h) {
        __builtin_amdgcn_s_barrier();
        if (wn == h) {
#pragma unroll
            for (int ti = 0; ti < 8; ++ti) {
#pragma unroll
                for (int tj = 0; tj < 8; ++tj) {
                    const int mloc = tj * 16 + l15;
                    const int g = wm * 32 + ti * 4 + quad;   // 8-B granule
                    const int gs = g ^ (mloc & 15);
                    f32x4 v = acc[ti][tj];
                    uint2 q2;
                    q2.x = (unsigned)f2bf(v[0]) | ((unsigned)f2bf(v[1]) << 16);
                    q2.y = (unsigned)f2bf(v[2]) | ((unsigned)f2bf(v[3]) << 16);
                    *(uint2*)(smem + mloc * 256 + gs * 4) = q2;
                }
            }
        }
        asm volatile("s_waitcnt lgkmcnt(0)" ::: "memory");
        __builtin_amdgcn_s_barrier();
        {
            const int r = tid >> 1;          // 0..127 (m within half-tile)
            const int h2 = tid & 1;          // half-row (128 shorts = 32 granules)
            unsigned short* grow = res + (size_t)(j0 + h * 128 + r) * 32768
                                       + i0 + h2 * 128;
            const unsigned short* lrow = smem + r * 256;
            const int rx = r & 15;
#pragma unroll
            for (int j = 0; j < 32; j += 2) {
                const int g0 = (h2 * 32 + j) ^ rx;
                const int g1 = (h2 * 32 + j + 1) ^ rx;
                uint2 u0 = *(const uint2*)(lrow + g0 * 4);
                uint2 u1 = *(const uint2*)(lrow + g1 * 4);
                uint4 q; q.x = u0.x; q.y = u0.y; q.z = u1.x; q.w = u1.y;
                *(uint4*)(grow + j * 4) = q;
            }
        }
        asm volatile("s_waitcnt lgkmcnt(0)" ::: "memory");
    }
}

// ---------------------------------------------------------------- finalize
__global__ __launch_bounds__(256) void k_final(
        const unsigned short* __restrict__ res, const float* __restrict__ mom,
        float* __restrict__ out) {
    __shared__ float hann[512];
    __shared__ float P0[128];
    __shared__ float P1[128];
    __shared__ float scl[129];          // scl[0]=0, scl[f+1]=mom/norm
    const int tid = threadIdx.x;
    const int m = blockIdx.x;
    const unsigned short* row = res + (size_t)m * 32768;

    hann[tid]       = 0.5f * (1.f - cosf(6.283185307179586f * (float)tid / 512.f));
    hann[tid + 256] = 0.5f * (1.f - cosf(6.283185307179586f * (float)(tid + 256) / 512.f));
    if (tid == 0) scl[0] = 0.f;
    __syncthreads();

    const int wave = tid >> 6, lane = tid & 63;
    const int ih = (lane & 31) * 8;     // within-chunk offset
    for (int cp = wave; cp < 64; cp += 4) {   // chunk pair: chunks 2cp, 2cp+1
        const unsigned short* p = row + cp * 512 + lane * 8;
        uint4 q = *(const uint4*)p;
        float s0 = 0.f, s1 = 0.f;
        const unsigned w[4] = {q.x, q.y, q.z, q.w};
#pragma unroll
        for (int j = 0; j < 4; ++j) {
            float v0 = bf2f((unsigned short)w[j]);
            float v1 = bf2f((unsigned short)(w[j] >> 16));
            float a0 = v0 * hann[ih + j * 2],       a1 = v1 * hann[ih + j * 2 + 1];
            float b0 = v0 * hann[256 + ih + j * 2], b1 = v1 * hann[256 + ih + j * 2 + 1];
            s0 += a0 * a0 + a1 * a1;
            s1 += b0 * b0 + b1 * b1;
        }
#pragma unroll
        for (int off = 1; off <= 16; off <<= 1) {     // reduce within 32-lane half
            s0 += __shfl_xor(s0, off, 64);
            s1 += __shfl_xor(s1, off, 64);
        }
        if ((lane & 31) == 0) {
            const int c = 2 * cp + (lane >> 5);
            P0[c] = s0; P1[c] = s1;
        }
    }
    __syncthreads();
    if (tid < 128) {
        const float n2 = P0[tid] + ((tid < 127) ? P1[tid + 1] : 0.f);
        scl[tid + 1] = mom[(size_t)m * 128 + tid] / (sqrtf(n2) + 1e-8f);
    }
    __syncthreads();

#pragma unroll 4
    for (int j = 0; j < 32; ++j) {
        const int s0 = j * 1024 + tid * 4;
        const int f1 = s0 >> 8, i1 = s0 & 255;
        const float sc1 = scl[f1 + 1];
        const float sc0 = scl[f1];
        uint2 rp = *(const uint2*)(row + s0);
        float4 o;
        o.x = bf2f((unsigned short)rp.x)         * (hann[i1]     * sc1 + hann[i1 + 256] * sc0);
        o.y = bf2f((unsigned short)(rp.x >> 16)) * (hann[i1 + 1] * sc1 + hann[i1 + 257] * sc0);
        o.z = bf2f((unsigned short)rp.y)         * (hann[i1 + 2] * sc1 + hann[i1 + 258] * sc0);
        o.w = bf2f((unsigned short)(rp.y >> 16)) * (hann[i1 + 3] * sc1 + hann[i1 + 259] * sc0);
        *(float4*)(out + (size_t)m * 32768 + s0) = o;
    }
}

extern "C" void kernel_launch(void* const* d_in, const int* in_sizes, int n_in,
                              void* d_out, int out_size, void* d_ws, size_t ws_size,
                              hipStream_t stream) {
    const float* x     = (const float*)d_in[0];
    const float* Wsel  = (const float*)d_in[1];
    const float* bsel  = (const float*)d_in[2];
    const float* Wmom  = (const float*)d_in[3];
    const float* bmom  = (const float*)d_in[4];
    const float* atoms = (const float*)d_in[5];

    float* out    = (float*)d_out;
    float* momout = out + (size_t)1024 * 32768;

    unsigned char* ws = (unsigned char*)d_ws;
    unsigned short* atomsT = (unsigned short*)(ws);                 // 64 MB
    unsigned short* sel    = (unsigned short*)(ws + 67108864);      //  2 MB
    unsigned short* res    = (unsigned short*)(ws + 69206016);      // 64 MB
    // transient head buffers inside the (not-yet-written) res region:
    float*          logits = (float*)res;                           // 4 MB
    unsigned short* xbf    = (unsigned short*)(ws + 69206016 + 4194304);
    unsigned short* wbf    = (unsigned short*)(ws + 69206016 + 4194304 + 262144);
    float*          WmomT  = (float*)(ws + 69206016 + 4194304 + 524288);

    k_convert<<<128, 256, 0, stream>>>(x, Wsel, Wmom, xbf, wbf, WmomT);
    k_head_gemm<<<dim3(8, 8), 256, 0, stream>>>(wbf, xbf, logits);
    k_softmax_mom<<<1024, 256, 0, stream>>>(logits, bsel, x, WmomT, bmom, sel, momout);
    k_transpose<<<dim3(512, 16), 256, 0, stream>>>(atoms, atomsT);
    k_gemm<<<512, 256, 0, stream>>>(atomsT, sel, res);
    k_final<<<1024, 256, 0, stream>>>(res, momout, out);
}

// Round 5
// 377.746 us; speedup vs baseline: 1.0426x; 1.0426x over previous
//
#include <hip/hip_runtime.h>

// RecurrentResonanceModel on MI355X.
// Pipeline:
//   k_convert    : x, W_sel fp32 -> bf16; Wmom -> WmomT fp32 (transposed)
//   k_head_gemm  : logits[m][a] = x[m][:] . Wsel[a][:]  (MFMA, f32 out)
//   k_softmax_mom: softmax(logits)+bsel -> sel bf16; mom head fp32
//   k_transpose  : atoms fp32 [A][S] -> bf16 [S][A]
//   k_gemm       : res[m][s] = sel[m][:] . atomsT[s][:]
//                  256x256 tile, BK=32, 8 waves (2s x 4m, 128x64/wave: the
//                  register-feasible max; 128x128/wave = VGPR 228 cliff,
//                  measured r4), 4-deep LDS K-tile rotation (128 KiB),
//                  counted vmcnt(8), XOR-swizzled LDS, setprio, XCD-bijective
//                  grid, swizzled LDS-staged epilogue.  [88.4 us measured]
//   k_final      : REGISTER-staged single pass: row (64 VGPR) loaded once,
//                  chunk norms P0/P1, then scale+overlap-add from registers.
//                  Saves 64 MB HBM re-read + one decode pass vs 2-pass.
//
// Sizes: M=1024 (B*E), L=128, A=1024, S=32768, F=128, W=512, HOP=256.
// d_out = [ out (1024*32768 f32) | mom (1024*128 f32) ]
// d_ws  = [ atomsT bf16 64MB | sel bf16 2MB | res bf16 64MB ]

typedef __attribute__((ext_vector_type(8))) short short8;
typedef __attribute__((ext_vector_type(4))) float f32x4;

typedef __attribute__((address_space(1))) void GV;
typedef __attribute__((address_space(3))) void LV;

__device__ __forceinline__ unsigned short f2bf(float f) {
    union { float f; unsigned u; } c; c.f = f;
    unsigned u = c.u;
    u = (u + 0x7FFFu + ((u >> 16) & 1u)) >> 16;   // RNE
    return (unsigned short)u;
}
__device__ __forceinline__ float bf2f(unsigned short h) {
    union { unsigned u; float f; } c; c.u = ((unsigned)h) << 16; return c.f;
}

// ---------------------------------------------------------------- convert
__global__ __launch_bounds__(256) void k_convert(
        const float* __restrict__ x, const float* __restrict__ Wsel,
        const float* __restrict__ Wmom,
        unsigned short* __restrict__ xbf, unsigned short* __restrict__ wbf,
        float* __restrict__ WmomT) {
    const int i = (blockIdx.x * 256 + threadIdx.x) * 4;
    {
        float4 v = *(const float4*)(x + i);
        uint2 q;
        q.x = (unsigned)f2bf(v.x) | ((unsigned)f2bf(v.y) << 16);
        q.y = (unsigned)f2bf(v.z) | ((unsigned)f2bf(v.w) << 16);
        *(uint2*)(xbf + i) = q;
    }
    {
        float4 v = *(const float4*)(Wsel + i);
        uint2 q;
        q.x = (unsigned)f2bf(v.x) | ((unsigned)f2bf(v.y) << 16);
        q.y = (unsigned)f2bf(v.z) | ((unsigned)f2bf(v.w) << 16);
        *(uint2*)(wbf + i) = q;
    }
    if (blockIdx.x < 8) {
        const int f  = blockIdx.x * 16 + (threadIdx.x >> 4);   // 0..127
        const int kc = (threadIdx.x & 15) * 8;                 // 0..120
        float4 a = *(const float4*)(Wmom + (size_t)f * 128 + kc);
        float4 b = *(const float4*)(Wmom + (size_t)f * 128 + kc + 4);
        WmomT[(kc + 0) * 128 + f] = a.x; WmomT[(kc + 1) * 128 + f] = a.y;
        WmomT[(kc + 2) * 128 + f] = a.z; WmomT[(kc + 3) * 128 + f] = a.w;
        WmomT[(kc + 4) * 128 + f] = b.x; WmomT[(kc + 5) * 128 + f] = b.y;
        WmomT[(kc + 6) * 128 + f] = b.z; WmomT[(kc + 7) * 128 + f] = b.w;
    }
}

// ---------------------------------------------------------------- head gemm
__global__ __launch_bounds__(256) void k_head_gemm(
        const unsigned short* __restrict__ A, const unsigned short* __restrict__ Bm,
        float* __restrict__ logits) {
    __shared__ __align__(16) unsigned short lA[128 * 32];
    __shared__ __align__(16) unsigned short lB[128 * 32];
    const int tid = threadIdx.x;
    const int wave = tid >> 6;
    const int lane = tid & 63;
    const int l15 = lane & 15, quad = lane >> 4;
    const int i0 = blockIdx.x * 128;   // a (Wsel rows)
    const int j0 = blockIdx.y * 128;   // m (x rows)
    const int wi = wave >> 1, wj = wave & 1;
    const int rsel = lane >> 2;
    const int koff = (lane & 3) * 8;

    f32x4 acc[4][4] = {};

    for (int kt = 0; kt < 4; ++kt) {
        const int kbase = kt * 32;
#pragma unroll
        for (int c = 0; c < 2; ++c) {
            const int row = c * 64 + wave * 16 + rsel;
            const unsigned short* ga = A + (size_t)(i0 + row) * 128 + kbase + koff;
            const unsigned short* gb = Bm + (size_t)(j0 + row) * 128 + kbase + koff;
            unsigned short* la = lA + (c * 64 + wave * 16) * 32;
            unsigned short* lb = lB + (c * 64 + wave * 16) * 32;
            __builtin_amdgcn_global_load_lds((GV*)ga, (LV*)la, 16, 0, 0);
            __builtin_amdgcn_global_load_lds((GV*)gb, (LV*)lb, 16, 0, 0);
        }
        __syncthreads();

        short8 af[4], bf[4];
#pragma unroll
        for (int ti = 0; ti < 4; ++ti)
            af[ti] = *(const short8*)(lA + (wi * 64 + ti * 16 + l15) * 32 + quad * 8);
#pragma unroll
        for (int tj = 0; tj < 4; ++tj)
            bf[tj] = *(const short8*)(lB + (wj * 64 + tj * 16 + l15) * 32 + quad * 8);
#pragma unroll
        for (int ti = 0; ti < 4; ++ti)
#pragma unroll
            for (int tj = 0; tj < 4; ++tj)
                acc[ti][tj] = __builtin_amdgcn_mfma_f32_16x16x32_bf16(
                    af[ti], bf[tj], acc[ti][tj], 0, 0, 0);
        __syncthreads();
    }

#pragma unroll
    for (int ti = 0; ti < 4; ++ti) {
#pragma unroll
        for (int tj = 0; tj < 4; ++tj) {
            const int mrow = j0 + wj * 64 + tj * 16 + l15;
            const int abase = i0 + wi * 64 + ti * 16 + quad * 4;
            f32x4 v = acc[ti][tj];
            float4 o; o.x = v[0]; o.y = v[1]; o.z = v[2]; o.w = v[3];
            *(float4*)(logits + (size_t)mrow * 1024 + abase) = o;
        }
    }
}

// ---------------------------------------------------------------- softmax+mom
__global__ __launch_bounds__(256) void k_softmax_mom(
        const float* __restrict__ logits_g, const float* __restrict__ bsel,
        const float* __restrict__ x, const float* __restrict__ WmomT,
        const float* __restrict__ bmom, unsigned short* __restrict__ sel,
        float* __restrict__ momout) {
    __shared__ float xs[128];
    __shared__ float logits[1024];
    __shared__ float mvals[128];
    __shared__ float wred[4];
    __shared__ float sstat[2];
    const int tid = threadIdx.x;
    const int m = blockIdx.x;

    if (tid < 32) *(float4*)&xs[tid * 4] = *(const float4*)(x + (size_t)m * 128 + tid * 4);
    for (int a = tid; a < 1024; a += 256)
        logits[a] = logits_g[(size_t)m * 1024 + a] + bsel[a];
    __syncthreads();

    if (tid < 128) {
        float acc = bmom[tid];
#pragma unroll 8
        for (int k = 0; k < 128; ++k)
            acc += xs[k] * WmomT[k * 128 + tid];     // lane-coalesced
        float sig = 1.f / (1.f + __expf(-acc));
        mvals[tid] = 0.2f + sig * 0.72f;      // BASE_RES + sigmoid*RES_FACTOR
    }

    float mx = -1e30f;
    for (int a = tid; a < 1024; a += 256) mx = fmaxf(mx, logits[a]);
#pragma unroll
    for (int off = 32; off; off >>= 1) mx = fmaxf(mx, __shfl_xor(mx, off, 64));
    if ((tid & 63) == 0) wred[tid >> 6] = mx;
    __syncthreads();
    if (tid == 0) sstat[0] = fmaxf(fmaxf(wred[0], wred[1]), fmaxf(wred[2], wred[3]));
    __syncthreads();
    mx = sstat[0];

    float psum = 0.f;
    for (int a = tid; a < 1024; a += 256) {
        float e = __expf(logits[a] - mx);
        logits[a] = e;
        psum += e;
    }
#pragma unroll
    for (int off = 32; off; off >>= 1) psum += __shfl_xor(psum, off, 64);
    if ((tid & 63) == 0) wred[tid >> 6] = psum;
    __syncthreads();
    if (tid == 0) sstat[1] = wred[0] + wred[1] + wred[2] + wred[3];
    __syncthreads();
    const float inv = 1.f / sstat[1];
    for (int a = tid; a < 1024; a += 256)
        sel[(size_t)m * 1024 + a] = f2bf(logits[a] * inv);

    // cumulative product into LDS (serial chain, one lane), then coalesced
    // 128-thread store (was: 128 serial scalar global stores).
    if (tid == 0) {
        float p = 1.f;
        for (int f = 0; f < 128; ++f) {
            p *= (mvals[f] + 1e-12f);
            mvals[f] = p;
        }
    }
    __syncthreads();
    if (tid < 128) momout[(size_t)m * 128 + tid] = mvals[tid];
}

// ---------------------------------------------------------------- transpose
__global__ __launch_bounds__(256) void k_transpose(
        const float* __restrict__ atoms, unsigned short* __restrict__ atomsT) {
    __shared__ float t[64][65];
    const int tid = threadIdx.x;
    const int s0 = blockIdx.x * 64;
    const int a0 = blockIdx.y * 64;

    {
        const int r0 = tid >> 4;
        const int c4 = (tid & 15) * 4;
        for (int rr = r0; rr < 64; rr += 16) {
            float4 v = *(const float4*)(atoms + (size_t)(a0 + rr) * 32768 + s0 + c4);
            t[rr][c4] = v.x; t[rr][c4 + 1] = v.y; t[rr][c4 + 2] = v.z; t[rr][c4 + 3] = v.w;
        }
    }
    __syncthreads();
    {
        const int sl = tid >> 2;
        const int seg = (tid & 3) * 16;
        unsigned short* dst = atomsT + (size_t)(s0 + sl) * 1024 + a0 + seg;
        unsigned pk[8];
#pragma unroll
        for (int i = 0; i < 16; i += 2) {
            unsigned short h0 = f2bf(t[seg + i][sl]);
            unsigned short h1 = f2bf(t[seg + i + 1][sl]);
            pk[i >> 1] = (unsigned)h0 | ((unsigned)h1 << 16);
        }
        uint4 q0; q0.x = pk[0]; q0.y = pk[1]; q0.z = pk[2]; q0.w = pk[3];
        uint4 q1; q1.x = pk[4]; q1.y = pk[5]; q1.z = pk[6]; q1.w = pk[7];
        *(uint4*)(dst) = q0;
        *(uint4*)(dst + 8) = q1;
    }
}

// ---------------------------------------------------------------- main gemm
// res[m][s] = sum_a sel[m][a] * atomsT[s][a].
// BM=256 (s), BN=256 (m), BK=32, 512 threads = 8 waves (2 s-halves x 4
// m-quarters), per-wave 128(s)x64(m), acc[8][4] f32x4.
// LDS: 4 K-tile buffers x (A 16KB + B 16KB) = exactly 128 KiB rotation;
// stage tile t+3 while computing tile t; one raw s_barrier per tile;
// steady-state s_waitcnt vmcnt(8) (2 tiles in flight), drained in the tail.
// Swizzle: within each 128-B super-row (2 rows of 32 k), 16-B granule
// G' = G ^ (q&7); applied to the *global source* of global_load_lds (LDS
// dest stays linear) and to the ds_read addresses (same involution).
__global__ __launch_bounds__(512, 2) void k_gemm(
        const unsigned short* __restrict__ A, const unsigned short* __restrict__ Bm,
        unsigned short* __restrict__ res) {
    // K-loop: 4 buffers x 16384 shorts (A 8192 | B 8192) = 131072 B.
    // Epilogue: [256][256] shorts (granule-XOR swizzled) = 131072 B (reuse).
    __shared__ __align__(16) unsigned short smem[65536];
    const int tid = threadIdx.x;
    const int lane = tid & 63;
    const int wave = tid >> 6;
    const int l15 = lane & 15, quad = lane >> 4;
    const int wm = wave >> 2;          // 0..1 : s half (128 rows)
    const int wn = wave & 3;           // 0..3 : m quarter (64 rows)

    // bijective XCD swizzle (512 blocks, 512%8==0): chunks of 64 per XCD,
    // m-fast inside a chunk so 4 m-tiles share each atomsT panel in L2.
    const int wg = ((blockIdx.x & 7) << 6) | (blockIdx.x >> 3);
    const int m_tile = wg & 3;         // 0..3
    const int s_tile = wg >> 2;        // 0..127
    const int i0 = s_tile << 8;        // s base (atomsT rows)
    const int j0 = m_tile << 8;        // m base (sel rows)

    // Staging: 2 load instrs per operand per tile; instr r covers LDS bytes
    // [r*8192 + tid*16, +16) of the op-buffer (linear dest; per-wave it is
    // uniform-base + lane*16 as required). That slot (q = byte>>7,
    // G' = (byte>>4)&7) holds content G = G'^(q&7): row = 2q + (G>>2),
    // k-granule g = G&3 -> pre-swizzled global source address.
    const unsigned short* gA[2];
    const unsigned short* gB[2];
    int st_ld[2];
#pragma unroll
    for (int r = 0; r < 2; ++r) {
        const int qq = r * 64 + (tid >> 3);
        const int Gs = (tid & 7) ^ (qq & 7);
        const int row = 2 * qq + (Gs >> 2);
        const int g8 = (Gs & 3) * 8;
        st_ld[r] = r * 4096 + tid * 8;                       // shorts
        gA[r] = A  + (size_t)(i0 + row) * 1024 + g8;
        gB[r] = Bm + (size_t)(j0 + row) * 1024 + g8;
    }

    // Fragment read offsets (swizzled): invariant across ti/tj; step 512
    // shorts (8 super-rows) per fragment index. Per-8-lane groups tile all 8
    // granule positions -> conflict-free ds_read_b128.
    const int Gp = (((l15 & 1) << 2) | quad) ^ (l15 >> 1);
    const int aoff = wm * 4096 + (l15 >> 1) * 64 + Gp * 8;   // shorts in A region
    const int boff = wn * 2048 + (l15 >> 1) * 64 + Gp * 8;   // shorts in B region

#define STAGE(T) {                                                            \
    unsigned short* bb = smem + ((T) & 3) * 16384;                            \
    const int kb = (T) * 32;                                                  \
    __builtin_amdgcn_global_load_lds((GV*)(gA[0] + kb), (LV*)(bb + st_ld[0]), 16, 0, 0); \
    __builtin_amdgcn_global_load_lds((GV*)(gA[1] + kb), (LV*)(bb + st_ld[1]), 16, 0, 0); \
    __builtin_amdgcn_global_load_lds((GV*)(gB[0] + kb), (LV*)(bb + 8192 + st_ld[0]), 16, 0, 0); \
    __builtin_amdgcn_global_load_lds((GV*)(gB[1] + kb), (LV*)(bb + 8192 + st_ld[1]), 16, 0, 0); }

#define TILE(T, VMC, DOSTAGE) {                                               \
    asm volatile("s_waitcnt vmcnt(" VMC ")" ::: "memory");                    \
    __builtin_amdgcn_s_barrier();                                             \
    if (DOSTAGE) STAGE((T) + 3);                                              \
    const unsigned short* bufA = smem + ((T) & 3) * 16384;                    \
    const unsigned short* bufB = bufA + 8192;                                 \
    short8 a8[8], b8[4];                                                      \
    _Pragma("unroll")                                                         \
    for (int tj = 0; tj < 4; ++tj)                                            \
        b8[tj] = *(const short8*)(bufB + boff + tj * 512);                    \
    _Pragma("unroll")                                                         \
    for (int ti = 0; ti < 8; ++ti)                                            \
        a8[ti] = *(const short8*)(bufA + aoff + ti * 512);                    \
    __builtin_amdgcn_s_setprio(1);                                            \
    _Pragma("unroll")                                                         \
    for (int ti = 0; ti < 8; ++ti)                                            \
    _Pragma("unroll")                                                         \
    for (int tj = 0; tj < 4; ++tj)                                            \
        acc[ti][tj] = __builtin_amdgcn_mfma_f32_16x16x32_bf16(                \
            a8[ti], b8[tj], acc[ti][tj], 0, 0, 0);                            \
    __builtin_amdgcn_s_setprio(0); }

    f32x4 acc[8][4] = {};

    STAGE(0); STAGE(1); STAGE(2);               // 12 loads in flight
    for (int t = 0; t < 29; ++t)
        TILE(t, "8", true);                     // stage t+3, keep 2 tiles in flight
    TILE(29, "8", false);
    TILE(30, "4", false);
    TILE(31, "0", false);

#undef TILE
#undef STAGE

    // Epilogue: acc -> LDS [256 m][256 s] bf16 with granule-XOR swizzle
    // (8-B granule g -> g ^ (mloc&15), involution; b64 ops at the 4-way
    // floor), then row-coalesced full-line global stores.
    asm volatile("s_waitcnt lgkmcnt(0)" ::: "memory");
    __builtin_amdgcn_s_barrier();
#pragma unroll
    for (int ti = 0; ti < 8; ++ti) {
#pragma unroll
        for (int tj = 0; tj < 4; ++tj) {
            const int mloc = wn * 64 + tj * 16 + l15;
            const int g = wm * 32 + ti * 4 + quad;          // 8-B granule index
            const int gs = g ^ (mloc & 15);
            f32x4 v = acc[ti][tj];
            uint2 q2;
            q2.x = (unsigned)f2bf(v[0]) | ((unsigned)f2bf(v[1]) << 16);
            q2.y = (unsigned)f2bf(v[2]) | ((unsigned)f2bf(v[3]) << 16);
            *(uint2*)(smem + mloc * 256 + gs * 4) = q2;
        }
    }
    asm volatile("s_waitcnt lgkmcnt(0)" ::: "memory");
    __builtin_amdgcn_s_barrier();
    {
        const int r = tid >> 1;          // 0..255 (m within tile)
        const int h = tid & 1;           // half-row (128 shorts = 32 granules)
        unsigned short* grow = res + (size_t)(j0 + r) * 32768 + i0 + h * 128;
        const unsigned short* lrow = smem + r * 256;
        const int rx = r & 15;
#pragma unroll
        for (int j = 0; j < 32; j += 2) {
            const int g0 = (h * 32 + j) ^ rx;
            const int g1 = (h * 32 + j + 1) ^ rx;
            uint2 u0 = *(const uint2*)(lrow + g0 * 4);
            uint2 u1 = *(const uint2*)(lrow + g1 * 4);
            uint4 q; q.x = u0.x; q.y = u0.y; q.z = u1.x; q.w = u1.y;
            *(uint4*)(grow + j * 4) = q;
        }
    }
}

// ---------------------------------------------------------------- finalize
// Register-staged single pass: each thread holds 128 shorts (16 uint4,
// statically indexed -> stays in VGPRs). Pass A computes per-chunk partial
// norms P0 (hann first half) / P1 (second half) from registers; pass B
// scales from the same registers and writes fp32. One 64 KB global read
// per row instead of two.  norm^2[f] = P0[f] + P1[f+1] (chunk 128 = pad).
__global__ __launch_bounds__(256) void k_final(
        const unsigned short* __restrict__ res, const float* __restrict__ mom,
        float* __restrict__ out) {
    __shared__ float hann[512];
    __shared__ float P0[128];
    __shared__ float P1[128];
    __shared__ float scl[129];          // scl[0]=0, scl[f+1]=mom/norm
    const int tid = threadIdx.x;
    const int m = blockIdx.x;
    const unsigned short* row = res + (size_t)m * 32768;

    hann[tid]       = 0.5f * (1.f - cosf(6.283185307179586f * (float)tid / 512.f));
    hann[tid + 256] = 0.5f * (1.f - cosf(6.283185307179586f * (float)(tid + 256) / 512.f));
    if (tid == 0) scl[0] = 0.f;
    __syncthreads();

    const int wave = tid >> 6, lane = tid & 63;
    const int ih = (lane & 31) * 8;     // within-chunk offset
    uint4 rv[16];
#pragma unroll
    for (int it = 0; it < 16; ++it) {   // chunk pair: chunks 2cp, 2cp+1
        const int cp = wave + it * 4;
        rv[it] = *(const uint4*)(row + cp * 512 + lane * 8);
        float s0 = 0.f, s1 = 0.f;
        const unsigned w[4] = {rv[it].x, rv[it].y, rv[it].z, rv[it].w};
#pragma unroll
        for (int j = 0; j < 4; ++j) {
            float v0 = bf2f((unsigned short)w[j]);
            float v1 = bf2f((unsigned short)(w[j] >> 16));
            float a0 = v0 * hann[ih + j * 2],       a1 = v1 * hann[ih + j * 2 + 1];
            float b0 = v0 * hann[256 + ih + j * 2], b1 = v1 * hann[256 + ih + j * 2 + 1];
            s0 += a0 * a0 + a1 * a1;
            s1 += b0 * b0 + b1 * b1;
        }
#pragma unroll
        for (int off = 1; off <= 16; off <<= 1) {     // reduce within 32-lane half
            s0 += __shfl_xor(s0, off, 64);
            s1 += __shfl_xor(s1, off, 64);
        }
        if ((lane & 31) == 0) {
            const int c = 2 * cp + (lane >> 5);
            P0[c] = s0; P1[c] = s1;
        }
    }
    __syncthreads();
    if (tid < 128) {
        const float n2 = P0[tid] + ((tid < 127) ? P1[tid + 1] : 0.f);
        scl[tid + 1] = mom[(size_t)m * 128 + tid] / (sqrtf(n2) + 1e-8f);
    }
    __syncthreads();

#pragma unroll
    for (int it = 0; it < 16; ++it) {
        const int cp = wave + it * 4;
        const int c = 2 * cp + (lane >> 5);       // s>>8 for all 8 elems
        const float sc1 = scl[c + 1];
        const float sc0 = scl[c];
        const unsigned w[4] = {rv[it].x, rv[it].y, rv[it].z, rv[it].w};
        float o[8];
#pragma unroll
        for (int j = 0; j < 4; ++j) {
            float v0 = bf2f((unsigned short)w[j]);
            float v1 = bf2f((unsigned short)(w[j] >> 16));
            const int i1 = ih + j * 2;
            o[j * 2]     = v0 * (hann[i1]     * sc1 + hann[i1 + 256] * sc0);
            o[j * 2 + 1] = v1 * (hann[i1 + 1] * sc1 + hann[i1 + 257] * sc0);
        }
        float4 o0; o0.x = o[0]; o0.y = o[1]; o0.z = o[2]; o0.w = o[3];
        float4 o1; o1.x = o[4]; o1.y = o[5]; o1.z = o[6]; o1.w = o[7];
        float* gp = out + (size_t)m * 32768 + cp * 512 + lane * 8;
        *(float4*)gp = o0;
        *(float4*)(gp + 4) = o1;
    }
}

extern "C" void kernel_launch(void* const* d_in, const int* in_sizes, int n_in,
                              void* d_out, int out_size, void* d_ws, size_t ws_size,
                              hipStream_t stream) {
    const float* x     = (const float*)d_in[0];
    const float* Wsel  = (const float*)d_in[1];
    const float* bsel  = (const float*)d_in[2];
    const float* Wmom  = (const float*)d_in[3];
    const float* bmom  = (const float*)d_in[4];
    const float* atoms = (const float*)d_in[5];

    float* out    = (float*)d_out;
    float* momout = out + (size_t)1024 * 32768;

    unsigned char* ws = (unsigned char*)d_ws;
    unsigned short* atomsT = (unsigned short*)(ws);                 // 64 MB
    unsigned short* sel    = (unsigned short*)(ws + 67108864);      //  2 MB
    unsigned short* res    = (unsigned short*)(ws + 69206016);      // 64 MB
    // transient head buffers inside the (not-yet-written) res region:
    float*          logits = (float*)res;                           // 4 MB
    unsigned short* xbf    = (unsigned short*)(ws + 69206016 + 4194304);
    unsigned short* wbf    = (unsigned short*)(ws + 69206016 + 4194304 + 262144);
    float*          WmomT  = (float*)(ws + 69206016 + 4194304 + 524288);

    k_convert<<<128, 256, 0, stream>>>(x, Wsel, Wmom, xbf, wbf, WmomT);
    k_head_gemm<<<dim3(8, 8), 256, 0, stream>>>(wbf, xbf, logits);
    k_softmax_mom<<<1024, 256, 0, stream>>>(logits, bsel, x, WmomT, bmom, sel, momout);
    k_transpose<<<dim3(512, 16), 256, 0, stream>>>(atoms, atomsT);
    k_gemm<<<512, 512, 0, stream>>>(atomsT, sel, res);
    k_final<<<1024, 256, 0, stream>>>(res, momout, out);
}